// Round 8
// baseline (381.794 us; speedup 1.0000x reference)
//
#include <hip/hip_runtime.h>
#include <hip/hip_fp16.h>
#include <type_traits>

#define D 128

constexpr int SCAN_CHUNK = 1024;
constexpr int NRANGE = 8;    // dst ranges (one per XCD via blockIdx%8 heuristic)
constexpr int NCHUNK = 64;   // edge chunks
constexpr int RRC = 6272;    // max nodes per range supported by LDS arrays

using short8 = __attribute__((ext_vector_type(8))) short;
using f32x4 = __attribute__((ext_vector_type(4))) float;

// split fp32 into hi/lo bf16 (truncation; residual exact in fp32)
__device__ inline void splitf(float v, unsigned short& h, unsigned short& l) {
    unsigned b = __float_as_uint(v);
    h = (unsigned short)(b >> 16);
    float fh = __uint_as_float(b & 0xffff0000u);
    float r = v - fh;
    l = (unsigned short)(__float_as_uint(r) >> 16);
}

// ---------------- CSR build: XCD-partitioned counting sort, no global atomics ----------------

__global__ __launch_bounds__(1024) void hist_count(
    const int* __restrict__ dst, int* __restrict__ hist,
    int n_edges, int n_nodes, int rr, int ch) {
    __shared__ int lh[RRC];
    int b = blockIdx.x;
    int r = b & (NRANGE - 1), c = b >> 3;
    int t = threadIdx.x;
    for (int i = t; i < rr; i += 1024) lh[i] = 0;
    __syncthreads();
    int lo = r * rr, hi = min(n_nodes, lo + rr);
    int e0 = c * ch, e1 = min(n_edges, e0 + ch);
    for (int e = e0 + t; e < e1; e += 1024) {
        int d = dst[e];
        if (d >= lo && d < hi) atomicAdd(&lh[d - lo], 1);
    }
    __syncthreads();
    int* gh = hist + (size_t)(r * NCHUNK + c) * rr;
    for (int i = t; i < rr; i += 1024) gh[i] = lh[i];
}

__global__ __launch_bounds__(256) void deg_sum(
    const int* __restrict__ hist, int* __restrict__ deg, int n_nodes, int rr) {
    int i = blockIdx.x * 256 + threadIdx.x;
    if (i >= n_nodes) return;
    int r = i / rr, ii = i - r * rr;
    int s = 0;
    for (int c = 0; c < NCHUNK; ++c) s += hist[(size_t)(r * NCHUNK + c) * rr + ii];
    deg[i] = s;
}

__global__ void partial_sums(const int* __restrict__ deg, int* __restrict__ partials, int n) {
    __shared__ int sdata[256];
    int b = blockIdx.x, t = threadIdx.x;
    int base = b * SCAN_CHUNK;
    int sum = 0;
    for (int i = t; i < SCAN_CHUNK; i += 256) {
        int idx = base + i;
        if (idx < n) sum += deg[idx];
    }
    sdata[t] = sum;
    __syncthreads();
    for (int st = 128; st > 0; st >>= 1) {
        if (t < st) sdata[t] += sdata[t + st];
        __syncthreads();
    }
    if (t == 0) partials[b] = sdata[0];
}

__global__ void scan_partials(int* __restrict__ partials, int nb, int* __restrict__ total) {
    if (threadIdx.x == 0 && blockIdx.x == 0) {
        int run = 0;
        for (int i = 0; i < nb; ++i) { int v = partials[i]; partials[i] = run; run += v; }
        *total = run;
    }
}

__global__ void scan_chunks(const int* __restrict__ deg, const int* __restrict__ partials,
                            int* __restrict__ row_ptr, float* __restrict__ inv_deg, int n) {
    __shared__ int soff[256];
    int b = blockIdx.x, t = threadIdx.x;
    int base = b * SCAN_CHUNK;
    int i0 = base + t * 4;
    int v[4];
    int s = 0;
#pragma unroll
    for (int j = 0; j < 4; ++j) {
        int idx = i0 + j;
        v[j] = (idx < n) ? deg[idx] : 0;
        s += v[j];
    }
    soff[t] = s;
    __syncthreads();
    for (int d = 1; d < 256; d <<= 1) {
        int val = (t >= d) ? soff[t - d] : 0;
        __syncthreads();
        soff[t] += val;
        __syncthreads();
    }
    int excl = soff[t] - s + partials[b];
#pragma unroll
    for (int j = 0; j < 4; ++j) {
        int idx = i0 + j;
        if (idx < n) {
            row_ptr[idx] = excl;
            int dv = v[j] > 1 ? v[j] : 1;
            inv_deg[idx] = 1.0f / (float)dv;
            excl += v[j];
        }
    }
}

__global__ __launch_bounds__(256) void base_fill(
    const int* __restrict__ hist, const int* __restrict__ row_ptr,
    int* __restrict__ base, int n_nodes, int rr) {
    int i = blockIdx.x * 256 + threadIdx.x;
    if (i >= n_nodes) return;
    int r = i / rr, ii = i - r * rr;
    int b = row_ptr[i];
    for (int c = 0; c < NCHUNK; ++c) {
        size_t idx = (size_t)(r * NCHUNK + c) * rr + ii;
        base[idx] = b;
        b += hist[idx];
    }
}

__global__ __launch_bounds__(1024) void fill_part(
    const int* __restrict__ src, const int* __restrict__ dst,
    const int* __restrict__ base, int* __restrict__ csr,
    int n_edges, int n_nodes, int rr, int ch) {
    __shared__ int cur[RRC];
    int b = blockIdx.x;
    int r = b & (NRANGE - 1), c = b >> 3;
    int t = threadIdx.x;
    const int* gb = base + (size_t)(r * NCHUNK + c) * rr;
    for (int i = t; i < rr; i += 1024) cur[i] = gb[i];
    __syncthreads();
    int lo = r * rr, hi = min(n_nodes, lo + rr);
    int e0 = c * ch, e1 = min(n_edges, e0 + ch);
    for (int e = e0 + t; e < e1; e += 1024) {
        int d = dst[e];
        if (d >= lo && d < hi) {
            int slot = atomicAdd(&cur[d - lo], 1);
            csr[slot] = src[e];
        }
    }
}

// ---------------- weight split+transpose: W[K=128][N] -> Wt_hi/lo [N][128] ----------------
struct WSplitArgs {
    const float* src[6];
    unsigned short* dh[6];
    unsigned short* dl[6];
    int n[6];
};

__global__ __launch_bounds__(256) void split_w(WSplitArgs a) {
    int m = blockIdx.y;
    int N = a.n[m];
    int e = blockIdx.x * 256 + threadIdx.x;
    if (e >= 128 * N) return;
    int sh = (N == 128) ? 7 : 6;
    int k = e >> sh;
    int n = e & (N - 1);
    float v = a.src[m][e];
    unsigned short h, l;
    splitf(v, h, l);
    a.dh[m][n * 128 + k] = h;
    a.dl[m][n * 128 + k] = l;
}

// ---------------- MFMA GEMM: P(fp16) = A@W1, Q(fp32) = A@W2 + bias ----------------
// BM=32 rows/block. ALL loads (B frags + A frags for both mt) issued up front ->
// exactly one memory wait per wave, then a straight 48-MFMA chain (R7 post-mortem:
// per-mt prefetch couldn't hide ~900cyc HBM latency behind ~200cyc of MFMA).
template <int BN, int NT, bool SPLITX>
__global__ __launch_bounds__(256) void gemm_mfma(
    const float* __restrict__ X,
    const unsigned short* __restrict__ Ah, const unsigned short* __restrict__ Al,
    const unsigned short* __restrict__ W1h, const unsigned short* __restrict__ W1l,
    const unsigned short* __restrict__ W2h, const unsigned short* __restrict__ W2l,
    const float* __restrict__ bias, __half* __restrict__ P, float* __restrict__ Q, int M) {
    const int tid = threadIdx.x;
    const int wave = tid >> 6;
    const int lane = tid & 63;
    const int l15 = lane & 15;
    const int q = lane >> 4;
    const int isQ = blockIdx.y;
    const unsigned short* Wh = isQ ? W2h : W1h;
    const unsigned short* Wl = isQ ? W2l : W1l;

    // B fragments: NT tiles x 4 k-chunks, hi+lo
    short8 Bh[NT][4], Bl[NT][4];
    float bvs[NT];
#pragma unroll
    for (int nt = 0; nt < NT; ++nt) {
        int n = (wave * NT + nt) * 16 + l15;
#pragma unroll
        for (int kt = 0; kt < 4; ++kt) {
            int off = n * 128 + kt * 32 + q * 8;
            Bh[nt][kt] = *(const short8*)(Wh + off);
            Bl[nt][kt] = *(const short8*)(Wl + off);
        }
        bvs[nt] = isQ ? bias[n] : 0.f;
    }

    const int m0 = blockIdx.x * 32;

    using AB = typename std::conditional<SPLITX, float4, short8>::type;
    AB buf[2][8];   // [mt][frag] — all loaded before any MFMA

#pragma unroll
    for (int mt = 0; mt < 2; ++mt) {
        int row = m0 + mt * 16 + l15;
        int rc = row < M ? row : M - 1;
        if constexpr (SPLITX) {
            const float4* xp = (const float4*)X + (size_t)rc * 32 + q * 2;
#pragma unroll
            for (int kt = 0; kt < 4; ++kt) {
                buf[mt][2 * kt + 0] = xp[kt * 8 + 0];
                buf[mt][2 * kt + 1] = xp[kt * 8 + 1];
            }
        } else {
            const unsigned short* ap = Ah + (size_t)rc * 128 + q * 8;
            const unsigned short* alp = Al + (size_t)rc * 128 + q * 8;
#pragma unroll
            for (int kt = 0; kt < 4; ++kt) {
                buf[mt][kt] = *(const short8*)(ap + kt * 32);
                buf[mt][4 + kt] = *(const short8*)(alp + kt * 32);
            }
        }
    }

#pragma unroll
    for (int mt = 0; mt < 2; ++mt) {
        f32x4 acc[NT];
#pragma unroll
        for (int nt = 0; nt < NT; ++nt) acc[nt] = (f32x4)(0.f);
#pragma unroll
        for (int kt = 0; kt < 4; ++kt) {
            short8 Afh, Afl;
            if constexpr (SPLITX) {
                float4 ra = buf[mt][2 * kt + 0];
                float4 rb = buf[mt][2 * kt + 1];
                float fv[8] = {ra.x, ra.y, ra.z, ra.w, rb.x, rb.y, rb.z, rb.w};
#pragma unroll
                for (int j = 0; j < 8; ++j) {
                    unsigned short h, l;
                    splitf(fv[j], h, l);
                    Afh[j] = (short)h;
                    Afl[j] = (short)l;
                }
            } else {
                Afh = buf[mt][kt];
                Afl = buf[mt][4 + kt];
            }
#pragma unroll
            for (int nt = 0; nt < NT; ++nt) {
                acc[nt] = __builtin_amdgcn_mfma_f32_16x16x32_bf16(Afh, Bh[nt][kt], acc[nt], 0, 0, 0);
                acc[nt] = __builtin_amdgcn_mfma_f32_16x16x32_bf16(Afh, Bl[nt][kt], acc[nt], 0, 0, 0);
                acc[nt] = __builtin_amdgcn_mfma_f32_16x16x32_bf16(Afl, Bh[nt][kt], acc[nt], 0, 0, 0);
            }
        }

        int orow = m0 + mt * 16 + q * 4;
#pragma unroll
        for (int nt = 0; nt < NT; ++nt) {
            int col = (wave * NT + nt) * 16 + l15;
#pragma unroll
            for (int r = 0; r < 4; ++r) {
                int rr = orow + r;
                if (rr < M) {
                    if (isQ) Q[(size_t)rr * BN + col] = acc[nt][r] + bvs[nt];
                    else P[(size_t)rr * BN + col] = __float2half(acc[nt][r]);
                }
            }
        }
    }
}

// ---------------- fused aggregation 128-dim, fp16 gather ----------------
__global__ __launch_bounds__(256) void agg_fused128(
    const __half* __restrict__ P, const float* __restrict__ Q,
    const int* __restrict__ row_ptr, const int* __restrict__ csr,
    const float* __restrict__ inv_deg, unsigned short* __restrict__ Hh,
    unsigned short* __restrict__ Hl, int n_nodes) {
    int node = (blockIdx.x * blockDim.x + threadIdx.x) >> 6;
    int lane = threadIdx.x & 63;
    if (node >= n_nodes) return;
    int beg = row_ptr[node], end = row_ptr[node + 1];
    const int half = lane >> 5;
    const int l = lane & 31;
    float a[4][4] = {};
    int e = beg;
    for (; e + 8 <= end; e += 8) {
#pragma unroll
        for (int j = 0; j < 4; ++j) {
            int s = csr[e + 2 * j + half];
            uint2 raw = *(const uint2*)(P + (size_t)s * 128 + l * 4);
            float2 f01 = __half22float2(*reinterpret_cast<__half2*>(&raw.x));
            float2 f23 = __half22float2(*reinterpret_cast<__half2*>(&raw.y));
            a[j][0] += f01.x; a[j][1] += f01.y; a[j][2] += f23.x; a[j][3] += f23.y;
        }
    }
    for (; e < end; e += 2) {
        int idx = e + half;
        if (idx < end) {
            int s = csr[idx];
            uint2 raw = *(const uint2*)(P + (size_t)s * 128 + l * 4);
            float2 f01 = __half22float2(*reinterpret_cast<__half2*>(&raw.x));
            float2 f23 = __half22float2(*reinterpret_cast<__half2*>(&raw.y));
            a[0][0] += f01.x; a[0][1] += f01.y; a[0][2] += f23.x; a[0][3] += f23.y;
        }
    }
    float s0 = (a[0][0] + a[1][0]) + (a[2][0] + a[3][0]);
    float s1 = (a[0][1] + a[1][1]) + (a[2][1] + a[3][1]);
    float s2 = (a[0][2] + a[1][2]) + (a[2][2] + a[3][2]);
    float s3 = (a[0][3] + a[1][3]) + (a[2][3] + a[3][3]);
    s0 += __shfl_xor(s0, 32);
    s1 += __shfl_xor(s1, 32);
    s2 += __shfl_xor(s2, 32);
    s3 += __shfl_xor(s3, 32);
    if (lane < 32) {
        float w = inv_deg[node];
        float4 qv = ((const float4*)Q)[(size_t)node * 32 + l];
        float h0 = fmaxf(fmaf(s0, w, qv.x), 0.f);
        float h1 = fmaxf(fmaf(s1, w, qv.y), 0.f);
        float h2 = fmaxf(fmaf(s2, w, qv.z), 0.f);
        float h3 = fmaxf(fmaf(s3, w, qv.w), 0.f);
        ushort4 hv, lv;
        splitf(h0, hv.x, lv.x);
        splitf(h1, hv.y, lv.y);
        splitf(h2, hv.z, lv.z);
        splitf(h3, hv.w, lv.w);
        ((ushort4*)Hh)[(size_t)node * 32 + l] = hv;
        ((ushort4*)Hl)[(size_t)node * 32 + l] = lv;
    }
}

// ---------------- fused aggregation 64-dim (fp16 gather) + output head ----------------
__global__ __launch_bounds__(256) void agg64_head(
    const __half* __restrict__ P, const float* __restrict__ Q,
    const int* __restrict__ row_ptr, const int* __restrict__ csr,
    const float* __restrict__ inv_deg, const float* __restrict__ Wo,
    const float* __restrict__ bo, float* __restrict__ out, int n_nodes) {
    int node = (blockIdx.x * blockDim.x + threadIdx.x) >> 6;
    int lane = threadIdx.x & 63;
    if (node >= n_nodes) return;
    int beg = row_ptr[node], end = row_ptr[node + 1];
    const int quarter = lane >> 4;
    const int l = lane & 15;
    float a[2][4] = {};
    int e = beg;
    for (; e + 8 <= end; e += 8) {
#pragma unroll
        for (int j = 0; j < 2; ++j) {
            int s = csr[e + 4 * j + quarter];
            uint2 raw = *(const uint2*)(P + (size_t)s * 64 + l * 4);
            float2 f01 = __half22float2(*reinterpret_cast<__half2*>(&raw.x));
            float2 f23 = __half22float2(*reinterpret_cast<__half2*>(&raw.y));
            a[j][0] += f01.x; a[j][1] += f01.y; a[j][2] += f23.x; a[j][3] += f23.y;
        }
    }
    for (; e < end; e += 4) {
        int idx = e + quarter;
        if (idx < end) {
            int s = csr[idx];
            uint2 raw = *(const uint2*)(P + (size_t)s * 64 + l * 4);
            float2 f01 = __half22float2(*reinterpret_cast<__half2*>(&raw.x));
            float2 f23 = __half22float2(*reinterpret_cast<__half2*>(&raw.y));
            a[0][0] += f01.x; a[0][1] += f01.y; a[0][2] += f23.x; a[0][3] += f23.y;
        }
    }
    float s0 = a[0][0] + a[1][0];
    float s1 = a[0][1] + a[1][1];
    float s2 = a[0][2] + a[1][2];
    float s3 = a[0][3] + a[1][3];
    s0 += __shfl_xor(s0, 16); s0 += __shfl_xor(s0, 32);
    s1 += __shfl_xor(s1, 16); s1 += __shfl_xor(s1, 32);
    s2 += __shfl_xor(s2, 16); s2 += __shfl_xor(s2, 32);
    s3 += __shfl_xor(s3, 16); s3 += __shfl_xor(s3, 32);
    if (lane < 16) {
        float w = inv_deg[node];
        float4 qv = ((const float4*)Q)[(size_t)node * 16 + l];
        float h0 = fmaxf(fmaf(s0, w, qv.x), 0.f);
        float h1 = fmaxf(fmaf(s1, w, qv.y), 0.f);
        float h2 = fmaxf(fmaf(s2, w, qv.z), 0.f);
        float h3 = fmaxf(fmaf(s3, w, qv.w), 0.f);
        const float4* Wo4 = (const float4*)Wo;
        float4 w0 = Wo4[4 * l + 0], w1 = Wo4[4 * l + 1], w2 = Wo4[4 * l + 2], w3 = Wo4[4 * l + 3];
        float c0 = h0 * w0.x + h1 * w1.x + h2 * w2.x + h3 * w3.x;
        float c1 = h0 * w0.y + h1 * w1.y + h2 * w2.y + h3 * w3.y;
        float c2 = h0 * w0.z + h1 * w1.z + h2 * w2.z + h3 * w3.z;
        float c3 = h0 * w0.w + h1 * w1.w + h2 * w2.w + h3 * w3.w;
#pragma unroll
        for (int m = 8; m > 0; m >>= 1) {
            c0 += __shfl_xor(c0, m);
            c1 += __shfl_xor(c1, m);
            c2 += __shfl_xor(c2, m);
            c3 += __shfl_xor(c3, m);
        }
        if (l == 0) {
            float4 r;
            r.x = c0 + bo[0];
            r.y = c1 + bo[1];
            r.z = c2 + bo[2];
            r.w = c3 + bo[3];
            ((float4*)out)[node] = r;
        }
    }
}

extern "C" void kernel_launch(void* const* d_in, const int* in_sizes, int n_in,
                              void* d_out, int out_size, void* d_ws, size_t ws_size,
                              hipStream_t stream) {
    const float* x = (const float*)d_in[0];
    const int* ei = (const int*)d_in[1];
    const float* wl0 = (const float*)d_in[3];
    const float* wr0 = (const float*)d_in[4];
    const float* b0 = (const float*)d_in[5];
    const float* wl1 = (const float*)d_in[6];
    const float* wr1 = (const float*)d_in[7];
    const float* b1 = (const float*)d_in[8];
    const float* wl2 = (const float*)d_in[9];
    const float* wr2 = (const float*)d_in[10];
    const float* b2 = (const float*)d_in[11];
    const float* wo = (const float*)d_in[12];
    const float* bo = (const float*)d_in[13];

    const int n_nodes = in_sizes[0] / D;   // 50000
    const int n_edges = in_sizes[1] / 2;   // 800000
    const int* srcp = ei;
    const int* dstp = ei + n_edges;

    char* ws = (char*)d_ws;
    size_t off = 0;
    auto carve = [&](size_t bytes) -> void* {
        void* p = ws + off;
        off = (off + bytes + 255) & ~(size_t)255;
        return p;
    };
    int* deg = (int*)carve((size_t)n_nodes * 4);
    int* row_ptr = (int*)carve((size_t)(n_nodes + 1) * 4);
    int* partials = (int*)carve(256 * 4);
    float* inv_deg = (float*)carve((size_t)n_nodes * 4);
    int* csr = (int*)carve((size_t)n_edges * 4);
    __half* Pbuf = (__half*)carve((size_t)n_nodes * D * 2);   // 12.8 MB
    float* Qbuf = (float*)carve((size_t)n_nodes * D * 4);     // 25.6 MB
    unsigned short* hh = (unsigned short*)carve((size_t)n_nodes * D * 2);
    unsigned short* hl = (unsigned short*)carve((size_t)n_nodes * D * 2);
    unsigned short* wt = (unsigned short*)carve((size_t)(4 * 128 * 128 + 2 * 64 * 128) * 2 * 2);
    unsigned short* wl0h = wt;
    unsigned short* wl0l = wl0h + 128 * 128;
    unsigned short* wr0h = wl0l + 128 * 128;
    unsigned short* wr0l = wr0h + 128 * 128;
    unsigned short* wl1h = wr0l + 128 * 128;
    unsigned short* wl1l = wl1h + 128 * 128;
    unsigned short* wr1h = wl1l + 128 * 128;
    unsigned short* wr1l = wr1h + 128 * 128;
    unsigned short* wl2h = wr1l + 128 * 128;
    unsigned short* wl2l = wl2h + 64 * 128;
    unsigned short* wr2h = wl2l + 64 * 128;
    unsigned short* wr2l = wr2h + 64 * 128;

    // CSR-build scratch aliases P/Q (dead until first GEMM):
    const int rr = (n_nodes + NRANGE - 1) / NRANGE;        // 6250
    const int ch = (n_edges + NCHUNK - 1) / NCHUNK;        // 12500
    int* hist = (int*)Qbuf;
    int* basep = (int*)Pbuf;

    const int nchunk_scan = (n_nodes + SCAN_CHUNK - 1) / SCAN_CHUNK;

    hist_count<<<NRANGE * NCHUNK, 1024, 0, stream>>>(dstp, hist, n_edges, n_nodes, rr, ch);
    deg_sum<<<(n_nodes + 255) / 256, 256, 0, stream>>>(hist, deg, n_nodes, rr);
    partial_sums<<<nchunk_scan, 256, 0, stream>>>(deg, partials, n_nodes);
    scan_partials<<<1, 64, 0, stream>>>(partials, nchunk_scan, row_ptr + n_nodes);
    scan_chunks<<<nchunk_scan, 256, 0, stream>>>(deg, partials, row_ptr, inv_deg, n_nodes);
    base_fill<<<(n_nodes + 255) / 256, 256, 0, stream>>>(hist, row_ptr, basep, n_nodes, rr);
    fill_part<<<NRANGE * NCHUNK, 1024, 0, stream>>>(srcp, dstp, basep, csr, n_edges, n_nodes, rr, ch);

    WSplitArgs wa;
    wa.src[0] = wl0; wa.dh[0] = wl0h; wa.dl[0] = wl0l; wa.n[0] = 128;
    wa.src[1] = wr0; wa.dh[1] = wr0h; wa.dl[1] = wr0l; wa.n[1] = 128;
    wa.src[2] = wl1; wa.dh[2] = wl1h; wa.dl[2] = wl1l; wa.n[2] = 128;
    wa.src[3] = wr1; wa.dh[3] = wr1h; wa.dl[3] = wr1l; wa.n[3] = 128;
    wa.src[4] = wl2; wa.dh[4] = wl2h; wa.dl[4] = wl2l; wa.n[4] = 64;
    wa.src[5] = wr2; wa.dh[5] = wr2h; wa.dl[5] = wr2l; wa.n[5] = 64;
    split_w<<<dim3(64, 6), 256, 0, stream>>>(wa);

    const int agg_blocks = (n_nodes * 64 + 255) / 256;
    const dim3 gemm_grid((n_nodes + 31) / 32, 2);

    // layer 0: A = x (fp32, split in-register)
    gemm_mfma<128, 2, true><<<gemm_grid, 256, 0, stream>>>(
        x, nullptr, nullptr, wl0h, wl0l, wr0h, wr0l, b0, Pbuf, Qbuf, n_nodes);
    agg_fused128<<<agg_blocks, 256, 0, stream>>>(Pbuf, Qbuf, row_ptr, csr, inv_deg, hh, hl, n_nodes);
    // layer 1
    gemm_mfma<128, 2, false><<<gemm_grid, 256, 0, stream>>>(
        nullptr, hh, hl, wl1h, wl1l, wr1h, wr1l, b1, Pbuf, Qbuf, n_nodes);
    agg_fused128<<<agg_blocks, 256, 0, stream>>>(Pbuf, Qbuf, row_ptr, csr, inv_deg, hh, hl, n_nodes);
    // layer 2 (BN=64)
    gemm_mfma<64, 1, false><<<gemm_grid, 256, 0, stream>>>(
        nullptr, hh, hl, wl2h, wl2l, wr2h, wr2l, b2, Pbuf, Qbuf, n_nodes);
    agg64_head<<<agg_blocks, 256, 0, stream>>>(Pbuf, Qbuf, row_ptr, csr, inv_deg,
                                               wo, bo, (float*)d_out, n_nodes);
}

// Round 9
// 358.488 us; speedup vs baseline: 1.0650x; 1.0650x over previous
//
#include <hip/hip_runtime.h>
#include <hip/hip_fp16.h>
#include <type_traits>

#define D 128

constexpr int SCAN_CHUNK = 1024;
constexpr int NRANGE = 8;    // dst ranges (one per XCD via blockIdx%8 heuristic)
constexpr int NCHUNK = 64;   // edge chunks
constexpr int RRC = 6272;    // max nodes per range supported by LDS arrays

using short8 = __attribute__((ext_vector_type(8))) short;
using f32x4 = __attribute__((ext_vector_type(4))) float;

// split fp32 into hi/lo bf16 (truncation; residual exact in fp32)
__device__ inline void splitf(float v, unsigned short& h, unsigned short& l) {
    unsigned b = __float_as_uint(v);
    h = (unsigned short)(b >> 16);
    float fh = __uint_as_float(b & 0xffff0000u);
    float r = v - fh;
    l = (unsigned short)(__float_as_uint(r) >> 16);
}

// ---------------- CSR build: XCD-partitioned counting sort, no global atomics ----------------

__global__ __launch_bounds__(1024) void hist_count(
    const int* __restrict__ dst, int* __restrict__ hist,
    int n_edges, int n_nodes, int rr, int ch) {
    __shared__ int lh[RRC];
    int b = blockIdx.x;
    int r = b & (NRANGE - 1), c = b >> 3;
    int t = threadIdx.x;
    for (int i = t; i < rr; i += 1024) lh[i] = 0;
    __syncthreads();
    int lo = r * rr, hi = min(n_nodes, lo + rr);
    int e0 = c * ch, e1 = min(n_edges, e0 + ch);
    for (int e = e0 + t; e < e1; e += 1024) {
        int d = dst[e];
        if (d >= lo && d < hi) atomicAdd(&lh[d - lo], 1);
    }
    __syncthreads();
    int* gh = hist + (size_t)(r * NCHUNK + c) * rr;
    for (int i = t; i < rr; i += 1024) gh[i] = lh[i];
}

__global__ __launch_bounds__(256) void deg_sum(
    const int* __restrict__ hist, int* __restrict__ deg, int n_nodes, int rr) {
    int i = blockIdx.x * 256 + threadIdx.x;
    if (i >= n_nodes) return;
    int r = i / rr, ii = i - r * rr;
    int s = 0;
    for (int c = 0; c < NCHUNK; ++c) s += hist[(size_t)(r * NCHUNK + c) * rr + ii];
    deg[i] = s;
}

__global__ void partial_sums(const int* __restrict__ deg, int* __restrict__ partials, int n) {
    __shared__ int sdata[256];
    int b = blockIdx.x, t = threadIdx.x;
    int base = b * SCAN_CHUNK;
    int sum = 0;
    for (int i = t; i < SCAN_CHUNK; i += 256) {
        int idx = base + i;
        if (idx < n) sum += deg[idx];
    }
    sdata[t] = sum;
    __syncthreads();
    for (int st = 128; st > 0; st >>= 1) {
        if (t < st) sdata[t] += sdata[t + st];
        __syncthreads();
    }
    if (t == 0) partials[b] = sdata[0];
}

__global__ void scan_partials(int* __restrict__ partials, int nb, int* __restrict__ total) {
    if (threadIdx.x == 0 && blockIdx.x == 0) {
        int run = 0;
        for (int i = 0; i < nb; ++i) { int v = partials[i]; partials[i] = run; run += v; }
        *total = run;
    }
}

__global__ void scan_chunks(const int* __restrict__ deg, const int* __restrict__ partials,
                            int* __restrict__ row_ptr, float* __restrict__ inv_deg, int n) {
    __shared__ int soff[256];
    int b = blockIdx.x, t = threadIdx.x;
    int base = b * SCAN_CHUNK;
    int i0 = base + t * 4;
    int v[4];
    int s = 0;
#pragma unroll
    for (int j = 0; j < 4; ++j) {
        int idx = i0 + j;
        v[j] = (idx < n) ? deg[idx] : 0;
        s += v[j];
    }
    soff[t] = s;
    __syncthreads();
    for (int d = 1; d < 256; d <<= 1) {
        int val = (t >= d) ? soff[t - d] : 0;
        __syncthreads();
        soff[t] += val;
        __syncthreads();
    }
    int excl = soff[t] - s + partials[b];
#pragma unroll
    for (int j = 0; j < 4; ++j) {
        int idx = i0 + j;
        if (idx < n) {
            row_ptr[idx] = excl;
            int dv = v[j] > 1 ? v[j] : 1;
            inv_deg[idx] = 1.0f / (float)dv;
            excl += v[j];
        }
    }
}

__global__ __launch_bounds__(256) void base_fill(
    const int* __restrict__ hist, const int* __restrict__ row_ptr,
    int* __restrict__ base, int n_nodes, int rr) {
    int i = blockIdx.x * 256 + threadIdx.x;
    if (i >= n_nodes) return;
    int r = i / rr, ii = i - r * rr;
    int b = row_ptr[i];
    for (int c = 0; c < NCHUNK; ++c) {
        size_t idx = (size_t)(r * NCHUNK + c) * rr + ii;
        base[idx] = b;
        b += hist[idx];
    }
}

__global__ __launch_bounds__(1024) void fill_part(
    const int* __restrict__ src, const int* __restrict__ dst,
    const int* __restrict__ base, int* __restrict__ csr,
    int n_edges, int n_nodes, int rr, int ch) {
    __shared__ int cur[RRC];
    int b = blockIdx.x;
    int r = b & (NRANGE - 1), c = b >> 3;
    int t = threadIdx.x;
    const int* gb = base + (size_t)(r * NCHUNK + c) * rr;
    for (int i = t; i < rr; i += 1024) cur[i] = gb[i];
    __syncthreads();
    int lo = r * rr, hi = min(n_nodes, lo + rr);
    int e0 = c * ch, e1 = min(n_edges, e0 + ch);
    for (int e = e0 + t; e < e1; e += 1024) {
        int d = dst[e];
        if (d >= lo && d < hi) {
            int slot = atomicAdd(&cur[d - lo], 1);
            csr[slot] = src[e];
        }
    }
}

// ---------------- weight split+transpose: W[K=128][N] -> Wt_hi/lo [N][128] ----------------
struct WSplitArgs {
    const float* src[6];
    unsigned short* dh[6];
    unsigned short* dl[6];
    int n[6];
};

__global__ __launch_bounds__(256) void split_w(WSplitArgs a) {
    int m = blockIdx.y;
    int N = a.n[m];
    int e = blockIdx.x * 256 + threadIdx.x;
    if (e >= 128 * N) return;
    int sh = (N == 128) ? 7 : 6;
    int k = e >> sh;
    int n = e & (N - 1);
    float v = a.src[m][e];
    unsigned short h, l;
    splitf(v, h, l);
    a.dh[m][n * 128 + k] = h;
    a.dl[m][n * 128 + k] = l;
}

// ---------------- MFMA GEMM (fused P+Q): P(fp16)=A@W1, Q(fp32)=A@W2+bias ----------------
// BM=32 rows/block, ONE block computes both outputs: A loaded once, B for BOTH
// weight matrices held in registers, 96 MFMAs amortize each A-load stall
// (R8 post-mortem: 48 MFMAs per stall at same occupancy was the limiter).
template <int BN, int NT, bool SPLITX>
__global__ __launch_bounds__(256) void gemm_mfma(
    const float* __restrict__ X,
    const unsigned short* __restrict__ Ah, const unsigned short* __restrict__ Al,
    const unsigned short* __restrict__ W1h, const unsigned short* __restrict__ W1l,
    const unsigned short* __restrict__ W2h, const unsigned short* __restrict__ W2l,
    const float* __restrict__ bias, __half* __restrict__ P, float* __restrict__ Q, int M) {
    const int tid = threadIdx.x;
    const int wave = tid >> 6;
    const int lane = tid & 63;
    const int l15 = lane & 15;
    const int q = lane >> 4;

    // B fragments for BOTH matrices: NT tiles x 4 k-chunks, hi+lo
    short8 B1h[NT][4], B1l[NT][4], B2h[NT][4], B2l[NT][4];
    float bvs[NT];
#pragma unroll
    for (int nt = 0; nt < NT; ++nt) {
        int n = (wave * NT + nt) * 16 + l15;
#pragma unroll
        for (int kt = 0; kt < 4; ++kt) {
            int off = n * 128 + kt * 32 + q * 8;
            B1h[nt][kt] = *(const short8*)(W1h + off);
            B1l[nt][kt] = *(const short8*)(W1l + off);
            B2h[nt][kt] = *(const short8*)(W2h + off);
            B2l[nt][kt] = *(const short8*)(W2l + off);
        }
        bvs[nt] = bias[n];
    }

    const int m0 = blockIdx.x * 32;

    using AB = typename std::conditional<SPLITX, float4, short8>::type;
    AB buf[2][8];   // [mt][frag] — all loaded before any MFMA

#pragma unroll
    for (int mt = 0; mt < 2; ++mt) {
        int row = m0 + mt * 16 + l15;
        int rc = row < M ? row : M - 1;
        if constexpr (SPLITX) {
            const float4* xp = (const float4*)X + (size_t)rc * 32 + q * 2;
#pragma unroll
            for (int kt = 0; kt < 4; ++kt) {
                buf[mt][2 * kt + 0] = xp[kt * 8 + 0];
                buf[mt][2 * kt + 1] = xp[kt * 8 + 1];
            }
        } else {
            const unsigned short* ap = Ah + (size_t)rc * 128 + q * 8;
            const unsigned short* alp = Al + (size_t)rc * 128 + q * 8;
#pragma unroll
            for (int kt = 0; kt < 4; ++kt) {
                buf[mt][kt] = *(const short8*)(ap + kt * 32);
                buf[mt][4 + kt] = *(const short8*)(alp + kt * 32);
            }
        }
    }

#pragma unroll
    for (int mt = 0; mt < 2; ++mt) {
        f32x4 acc1[NT], acc2[NT];
#pragma unroll
        for (int nt = 0; nt < NT; ++nt) {
            acc1[nt] = (f32x4)(0.f);
            acc2[nt] = (f32x4)(0.f);
        }
#pragma unroll
        for (int kt = 0; kt < 4; ++kt) {
            short8 Afh, Afl;
            if constexpr (SPLITX) {
                float4 ra = buf[mt][2 * kt + 0];
                float4 rb = buf[mt][2 * kt + 1];
                float fv[8] = {ra.x, ra.y, ra.z, ra.w, rb.x, rb.y, rb.z, rb.w};
#pragma unroll
                for (int j = 0; j < 8; ++j) {
                    unsigned short h, l;
                    splitf(fv[j], h, l);
                    Afh[j] = (short)h;
                    Afl[j] = (short)l;
                }
            } else {
                Afh = buf[mt][kt];
                Afl = buf[mt][4 + kt];
            }
#pragma unroll
            for (int nt = 0; nt < NT; ++nt) {
                acc1[nt] = __builtin_amdgcn_mfma_f32_16x16x32_bf16(Afh, B1h[nt][kt], acc1[nt], 0, 0, 0);
                acc1[nt] = __builtin_amdgcn_mfma_f32_16x16x32_bf16(Afh, B1l[nt][kt], acc1[nt], 0, 0, 0);
                acc1[nt] = __builtin_amdgcn_mfma_f32_16x16x32_bf16(Afl, B1h[nt][kt], acc1[nt], 0, 0, 0);
                acc2[nt] = __builtin_amdgcn_mfma_f32_16x16x32_bf16(Afh, B2h[nt][kt], acc2[nt], 0, 0, 0);
                acc2[nt] = __builtin_amdgcn_mfma_f32_16x16x32_bf16(Afh, B2l[nt][kt], acc2[nt], 0, 0, 0);
                acc2[nt] = __builtin_amdgcn_mfma_f32_16x16x32_bf16(Afl, B2h[nt][kt], acc2[nt], 0, 0, 0);
            }
        }

        int orow = m0 + mt * 16 + q * 4;
#pragma unroll
        for (int nt = 0; nt < NT; ++nt) {
            int col = (wave * NT + nt) * 16 + l15;
#pragma unroll
            for (int r = 0; r < 4; ++r) {
                int rr = orow + r;
                if (rr < M) {
                    P[(size_t)rr * BN + col] = __float2half(acc1[nt][r]);
                    Q[(size_t)rr * BN + col] = acc2[nt][r] + bvs[nt];
                }
            }
        }
    }
}

// ---------------- fused aggregation 128-dim, fp16 gather ----------------
__global__ __launch_bounds__(256) void agg_fused128(
    const __half* __restrict__ P, const float* __restrict__ Q,
    const int* __restrict__ row_ptr, const int* __restrict__ csr,
    const float* __restrict__ inv_deg, unsigned short* __restrict__ Hh,
    unsigned short* __restrict__ Hl, int n_nodes) {
    int node = (blockIdx.x * blockDim.x + threadIdx.x) >> 6;
    int lane = threadIdx.x & 63;
    if (node >= n_nodes) return;
    int beg = row_ptr[node], end = row_ptr[node + 1];
    const int half = lane >> 5;
    const int l = lane & 31;
    float a[4][4] = {};
    int e = beg;
    for (; e + 8 <= end; e += 8) {
#pragma unroll
        for (int j = 0; j < 4; ++j) {
            int s = csr[e + 2 * j + half];
            uint2 raw = *(const uint2*)(P + (size_t)s * 128 + l * 4);
            float2 f01 = __half22float2(*reinterpret_cast<__half2*>(&raw.x));
            float2 f23 = __half22float2(*reinterpret_cast<__half2*>(&raw.y));
            a[j][0] += f01.x; a[j][1] += f01.y; a[j][2] += f23.x; a[j][3] += f23.y;
        }
    }
    for (; e < end; e += 2) {
        int idx = e + half;
        if (idx < end) {
            int s = csr[idx];
            uint2 raw = *(const uint2*)(P + (size_t)s * 128 + l * 4);
            float2 f01 = __half22float2(*reinterpret_cast<__half2*>(&raw.x));
            float2 f23 = __half22float2(*reinterpret_cast<__half2*>(&raw.y));
            a[0][0] += f01.x; a[0][1] += f01.y; a[0][2] += f23.x; a[0][3] += f23.y;
        }
    }
    float s0 = (a[0][0] + a[1][0]) + (a[2][0] + a[3][0]);
    float s1 = (a[0][1] + a[1][1]) + (a[2][1] + a[3][1]);
    float s2 = (a[0][2] + a[1][2]) + (a[2][2] + a[3][2]);
    float s3 = (a[0][3] + a[1][3]) + (a[2][3] + a[3][3]);
    s0 += __shfl_xor(s0, 32);
    s1 += __shfl_xor(s1, 32);
    s2 += __shfl_xor(s2, 32);
    s3 += __shfl_xor(s3, 32);
    if (lane < 32) {
        float w = inv_deg[node];
        float4 qv = ((const float4*)Q)[(size_t)node * 32 + l];
        float h0 = fmaxf(fmaf(s0, w, qv.x), 0.f);
        float h1 = fmaxf(fmaf(s1, w, qv.y), 0.f);
        float h2 = fmaxf(fmaf(s2, w, qv.z), 0.f);
        float h3 = fmaxf(fmaf(s3, w, qv.w), 0.f);
        ushort4 hv, lv;
        splitf(h0, hv.x, lv.x);
        splitf(h1, hv.y, lv.y);
        splitf(h2, hv.z, lv.z);
        splitf(h3, hv.w, lv.w);
        ((ushort4*)Hh)[(size_t)node * 32 + l] = hv;
        ((ushort4*)Hl)[(size_t)node * 32 + l] = lv;
    }
}

// ---------------- fused aggregation 64-dim (fp16 gather) + output head ----------------
__global__ __launch_bounds__(256) void agg64_head(
    const __half* __restrict__ P, const float* __restrict__ Q,
    const int* __restrict__ row_ptr, const int* __restrict__ csr,
    const float* __restrict__ inv_deg, const float* __restrict__ Wo,
    const float* __restrict__ bo, float* __restrict__ out, int n_nodes) {
    int node = (blockIdx.x * blockDim.x + threadIdx.x) >> 6;
    int lane = threadIdx.x & 63;
    if (node >= n_nodes) return;
    int beg = row_ptr[node], end = row_ptr[node + 1];
    const int quarter = lane >> 4;
    const int l = lane & 15;
    float a[2][4] = {};
    int e = beg;
    for (; e + 8 <= end; e += 8) {
#pragma unroll
        for (int j = 0; j < 2; ++j) {
            int s = csr[e + 4 * j + quarter];
            uint2 raw = *(const uint2*)(P + (size_t)s * 64 + l * 4);
            float2 f01 = __half22float2(*reinterpret_cast<__half2*>(&raw.x));
            float2 f23 = __half22float2(*reinterpret_cast<__half2*>(&raw.y));
            a[j][0] += f01.x; a[j][1] += f01.y; a[j][2] += f23.x; a[j][3] += f23.y;
        }
    }
    for (; e < end; e += 4) {
        int idx = e + quarter;
        if (idx < end) {
            int s = csr[idx];
            uint2 raw = *(const uint2*)(P + (size_t)s * 64 + l * 4);
            float2 f01 = __half22float2(*reinterpret_cast<__half2*>(&raw.x));
            float2 f23 = __half22float2(*reinterpret_cast<__half2*>(&raw.y));
            a[0][0] += f01.x; a[0][1] += f01.y; a[0][2] += f23.x; a[0][3] += f23.y;
        }
    }
    float s0 = a[0][0] + a[1][0];
    float s1 = a[0][1] + a[1][1];
    float s2 = a[0][2] + a[1][2];
    float s3 = a[0][3] + a[1][3];
    s0 += __shfl_xor(s0, 16); s0 += __shfl_xor(s0, 32);
    s1 += __shfl_xor(s1, 16); s1 += __shfl_xor(s1, 32);
    s2 += __shfl_xor(s2, 16); s2 += __shfl_xor(s2, 32);
    s3 += __shfl_xor(s3, 16); s3 += __shfl_xor(s3, 32);
    if (lane < 16) {
        float w = inv_deg[node];
        float4 qv = ((const float4*)Q)[(size_t)node * 16 + l];
        float h0 = fmaxf(fmaf(s0, w, qv.x), 0.f);
        float h1 = fmaxf(fmaf(s1, w, qv.y), 0.f);
        float h2 = fmaxf(fmaf(s2, w, qv.z), 0.f);
        float h3 = fmaxf(fmaf(s3, w, qv.w), 0.f);
        const float4* Wo4 = (const float4*)Wo;
        float4 w0 = Wo4[4 * l + 0], w1 = Wo4[4 * l + 1], w2 = Wo4[4 * l + 2], w3 = Wo4[4 * l + 3];
        float c0 = h0 * w0.x + h1 * w1.x + h2 * w2.x + h3 * w3.x;
        float c1 = h0 * w0.y + h1 * w1.y + h2 * w2.y + h3 * w3.y;
        float c2 = h0 * w0.z + h1 * w1.z + h2 * w2.z + h3 * w3.z;
        float c3 = h0 * w0.w + h1 * w1.w + h2 * w2.w + h3 * w3.w;
#pragma unroll
        for (int m = 8; m > 0; m >>= 1) {
            c0 += __shfl_xor(c0, m);
            c1 += __shfl_xor(c1, m);
            c2 += __shfl_xor(c2, m);
            c3 += __shfl_xor(c3, m);
        }
        if (l == 0) {
            float4 r;
            r.x = c0 + bo[0];
            r.y = c1 + bo[1];
            r.z = c2 + bo[2];
            r.w = c3 + bo[3];
            ((float4*)out)[node] = r;
        }
    }
}

extern "C" void kernel_launch(void* const* d_in, const int* in_sizes, int n_in,
                              void* d_out, int out_size, void* d_ws, size_t ws_size,
                              hipStream_t stream) {
    const float* x = (const float*)d_in[0];
    const int* ei = (const int*)d_in[1];
    const float* wl0 = (const float*)d_in[3];
    const float* wr0 = (const float*)d_in[4];
    const float* b0 = (const float*)d_in[5];
    const float* wl1 = (const float*)d_in[6];
    const float* wr1 = (const float*)d_in[7];
    const float* b1 = (const float*)d_in[8];
    const float* wl2 = (const float*)d_in[9];
    const float* wr2 = (const float*)d_in[10];
    const float* b2 = (const float*)d_in[11];
    const float* wo = (const float*)d_in[12];
    const float* bo = (const float*)d_in[13];

    const int n_nodes = in_sizes[0] / D;   // 50000
    const int n_edges = in_sizes[1] / 2;   // 800000
    const int* srcp = ei;
    const int* dstp = ei + n_edges;

    char* ws = (char*)d_ws;
    size_t off = 0;
    auto carve = [&](size_t bytes) -> void* {
        void* p = ws + off;
        off = (off + bytes + 255) & ~(size_t)255;
        return p;
    };
    int* deg = (int*)carve((size_t)n_nodes * 4);
    int* row_ptr = (int*)carve((size_t)(n_nodes + 1) * 4);
    int* partials = (int*)carve(256 * 4);
    float* inv_deg = (float*)carve((size_t)n_nodes * 4);
    int* csr = (int*)carve((size_t)n_edges * 4);
    __half* Pbuf = (__half*)carve((size_t)n_nodes * D * 2);   // 12.8 MB
    float* Qbuf = (float*)carve((size_t)n_nodes * D * 4);     // 25.6 MB
    unsigned short* hh = (unsigned short*)carve((size_t)n_nodes * D * 2);
    unsigned short* hl = (unsigned short*)carve((size_t)n_nodes * D * 2);
    unsigned short* wt = (unsigned short*)carve((size_t)(4 * 128 * 128 + 2 * 64 * 128) * 2 * 2);
    unsigned short* wl0h = wt;
    unsigned short* wl0l = wl0h + 128 * 128;
    unsigned short* wr0h = wl0l + 128 * 128;
    unsigned short* wr0l = wr0h + 128 * 128;
    unsigned short* wl1h = wr0l + 128 * 128;
    unsigned short* wl1l = wl1h + 128 * 128;
    unsigned short* wr1h = wl1l + 128 * 128;
    unsigned short* wr1l = wr1h + 128 * 128;
    unsigned short* wl2h = wr1l + 128 * 128;
    unsigned short* wl2l = wl2h + 64 * 128;
    unsigned short* wr2h = wl2l + 64 * 128;
    unsigned short* wr2l = wr2h + 64 * 128;

    // CSR-build scratch aliases P/Q (dead until first GEMM):
    const int rr = (n_nodes + NRANGE - 1) / NRANGE;        // 6250
    const int ch = (n_edges + NCHUNK - 1) / NCHUNK;        // 12500
    int* hist = (int*)Qbuf;
    int* basep = (int*)Pbuf;

    const int nchunk_scan = (n_nodes + SCAN_CHUNK - 1) / SCAN_CHUNK;

    hist_count<<<NRANGE * NCHUNK, 1024, 0, stream>>>(dstp, hist, n_edges, n_nodes, rr, ch);
    deg_sum<<<(n_nodes + 255) / 256, 256, 0, stream>>>(hist, deg, n_nodes, rr);
    partial_sums<<<nchunk_scan, 256, 0, stream>>>(deg, partials, n_nodes);
    scan_partials<<<1, 64, 0, stream>>>(partials, nchunk_scan, row_ptr + n_nodes);
    scan_chunks<<<nchunk_scan, 256, 0, stream>>>(deg, partials, row_ptr, inv_deg, n_nodes);
    base_fill<<<(n_nodes + 255) / 256, 256, 0, stream>>>(hist, row_ptr, basep, n_nodes, rr);
    fill_part<<<NRANGE * NCHUNK, 1024, 0, stream>>>(srcp, dstp, basep, csr, n_edges, n_nodes, rr, ch);

    WSplitArgs wa;
    wa.src[0] = wl0; wa.dh[0] = wl0h; wa.dl[0] = wl0l; wa.n[0] = 128;
    wa.src[1] = wr0; wa.dh[1] = wr0h; wa.dl[1] = wr0l; wa.n[1] = 128;
    wa.src[2] = wl1; wa.dh[2] = wl1h; wa.dl[2] = wl1l; wa.n[2] = 128;
    wa.src[3] = wr1; wa.dh[3] = wr1h; wa.dl[3] = wr1l; wa.n[3] = 128;
    wa.src[4] = wl2; wa.dh[4] = wl2h; wa.dl[4] = wl2l; wa.n[4] = 64;
    wa.src[5] = wr2; wa.dh[5] = wr2h; wa.dl[5] = wr2l; wa.n[5] = 64;
    split_w<<<dim3(64, 6), 256, 0, stream>>>(wa);

    const int agg_blocks = (n_nodes * 64 + 255) / 256;
    const int gemm_blocks = (n_nodes + 31) / 32;

    // layer 0: A = x (fp32, split in-register)
    gemm_mfma<128, 2, true><<<gemm_blocks, 256, 0, stream>>>(
        x, nullptr, nullptr, wl0h, wl0l, wr0h, wr0l, b0, Pbuf, Qbuf, n_nodes);
    agg_fused128<<<agg_blocks, 256, 0, stream>>>(Pbuf, Qbuf, row_ptr, csr, inv_deg, hh, hl, n_nodes);
    // layer 1
    gemm_mfma<128, 2, false><<<gemm_blocks, 256, 0, stream>>>(
        nullptr, hh, hl, wl1h, wl1l, wr1h, wr1l, b1, Pbuf, Qbuf, n_nodes);
    agg_fused128<<<agg_blocks, 256, 0, stream>>>(Pbuf, Qbuf, row_ptr, csr, inv_deg, hh, hl, n_nodes);
    // layer 2 (BN=64)
    gemm_mfma<64, 1, false><<<gemm_blocks, 256, 0, stream>>>(
        nullptr, hh, hl, wl2h, wl2l, wr2h, wr2l, b2, Pbuf, Qbuf, n_nodes);
    agg64_head<<<agg_blocks, 256, 0, stream>>>(Pbuf, Qbuf, row_ptr, csr, inv_deg,
                                               wo, bo, (float*)d_out, n_nodes);
}

// Round 10
// 319.320 us; speedup vs baseline: 1.1956x; 1.1227x over previous
//
#include <hip/hip_runtime.h>
#include <hip/hip_fp16.h>

#define D 128

constexpr int SCAN_CHUNK = 1024;
constexpr int NRANGE = 8;    // dst ranges (one per XCD via blockIdx%8 heuristic)
constexpr int NCHUNK = 64;   // edge chunks
constexpr int RRC = 6272;    // max nodes per range supported by LDS arrays

using short8 = __attribute__((ext_vector_type(8))) short;
using f32x4 = __attribute__((ext_vector_type(4))) float;

// split fp32 into hi/lo bf16 (truncation; residual exact in fp32)
__device__ inline void splitf(float v, unsigned short& h, unsigned short& l) {
    unsigned b = __float_as_uint(v);
    h = (unsigned short)(b >> 16);
    float fh = __uint_as_float(b & 0xffff0000u);
    float r = v - fh;
    l = (unsigned short)(__float_as_uint(r) >> 16);
}

// ---------------- CSR build: XCD-partitioned counting sort, no global atomics ----------------

__global__ __launch_bounds__(1024) void hist_count(
    const int* __restrict__ dst, int* __restrict__ hist,
    int n_edges, int n_nodes, int rr, int ch) {
    __shared__ int lh[RRC];
    int b = blockIdx.x;
    int r = b & (NRANGE - 1), c = b >> 3;
    int t = threadIdx.x;
    for (int i = t; i < rr; i += 1024) lh[i] = 0;
    __syncthreads();
    int lo = r * rr, hi = min(n_nodes, lo + rr);
    int e0 = c * ch, e1 = min(n_edges, e0 + ch);
    for (int e = e0 + t; e < e1; e += 1024) {
        int d = dst[e];
        if (d >= lo && d < hi) atomicAdd(&lh[d - lo], 1);
    }
    __syncthreads();
    int* gh = hist + (size_t)(r * NCHUNK + c) * rr;
    for (int i = t; i < rr; i += 1024) gh[i] = lh[i];
}

__global__ __launch_bounds__(256) void deg_sum(
    const int* __restrict__ hist, int* __restrict__ deg, int n_nodes, int rr) {
    int i = blockIdx.x * 256 + threadIdx.x;
    if (i >= n_nodes) return;
    int r = i / rr, ii = i - r * rr;
    int s = 0;
    for (int c = 0; c < NCHUNK; ++c) s += hist[(size_t)(r * NCHUNK + c) * rr + ii];
    deg[i] = s;
}

__global__ void partial_sums(const int* __restrict__ deg, int* __restrict__ partials, int n) {
    __shared__ int sdata[256];
    int b = blockIdx.x, t = threadIdx.x;
    int base = b * SCAN_CHUNK;
    int sum = 0;
    for (int i = t; i < SCAN_CHUNK; i += 256) {
        int idx = base + i;
        if (idx < n) sum += deg[idx];
    }
    sdata[t] = sum;
    __syncthreads();
    for (int st = 128; st > 0; st >>= 1) {
        if (t < st) sdata[t] += sdata[t + st];
        __syncthreads();
    }
    if (t == 0) partials[b] = sdata[0];
}

__global__ void scan_partials(int* __restrict__ partials, int nb, int* __restrict__ total) {
    if (threadIdx.x == 0 && blockIdx.x == 0) {
        int run = 0;
        for (int i = 0; i < nb; ++i) { int v = partials[i]; partials[i] = run; run += v; }
        *total = run;
    }
}

__global__ void scan_chunks(const int* __restrict__ deg, const int* __restrict__ partials,
                            int* __restrict__ row_ptr, float* __restrict__ inv_deg, int n) {
    __shared__ int soff[256];
    int b = blockIdx.x, t = threadIdx.x;
    int base = b * SCAN_CHUNK;
    int i0 = base + t * 4;
    int v[4];
    int s = 0;
#pragma unroll
    for (int j = 0; j < 4; ++j) {
        int idx = i0 + j;
        v[j] = (idx < n) ? deg[idx] : 0;
        s += v[j];
    }
    soff[t] = s;
    __syncthreads();
    for (int d = 1; d < 256; d <<= 1) {
        int val = (t >= d) ? soff[t - d] : 0;
        __syncthreads();
        soff[t] += val;
        __syncthreads();
    }
    int excl = soff[t] - s + partials[b];
#pragma unroll
    for (int j = 0; j < 4; ++j) {
        int idx = i0 + j;
        if (idx < n) {
            row_ptr[idx] = excl;
            int dv = v[j] > 1 ? v[j] : 1;
            inv_deg[idx] = 1.0f / (float)dv;
            excl += v[j];
        }
    }
}

__global__ __launch_bounds__(256) void base_fill(
    const int* __restrict__ hist, const int* __restrict__ row_ptr,
    int* __restrict__ base, int n_nodes, int rr) {
    int i = blockIdx.x * 256 + threadIdx.x;
    if (i >= n_nodes) return;
    int r = i / rr, ii = i - r * rr;
    int b = row_ptr[i];
    for (int c = 0; c < NCHUNK; ++c) {
        size_t idx = (size_t)(r * NCHUNK + c) * rr + ii;
        base[idx] = b;
        b += hist[idx];
    }
}

__global__ __launch_bounds__(1024) void fill_part(
    const int* __restrict__ src, const int* __restrict__ dst,
    const int* __restrict__ base, int* __restrict__ csr,
    int n_edges, int n_nodes, int rr, int ch) {
    __shared__ int cur[RRC];
    int b = blockIdx.x;
    int r = b & (NRANGE - 1), c = b >> 3;
    int t = threadIdx.x;
    const int* gb = base + (size_t)(r * NCHUNK + c) * rr;
    for (int i = t; i < rr; i += 1024) cur[i] = gb[i];
    __syncthreads();
    int lo = r * rr, hi = min(n_nodes, lo + rr);
    int e0 = c * ch, e1 = min(n_edges, e0 + ch);
    for (int e = e0 + t; e < e1; e += 1024) {
        int d = dst[e];
        if (d >= lo && d < hi) {
            int slot = atomicAdd(&cur[d - lo], 1);
            csr[slot] = src[e];
        }
    }
}

// ---------------- weight split+transpose: W[K=128][N] -> Wt_hi/lo [N][128] ----------------
struct WSplitArgs {
    const float* src[6];
    unsigned short* dh[6];
    unsigned short* dl[6];
    int n[6];
};

__global__ __launch_bounds__(256) void split_w(WSplitArgs a) {
    int m = blockIdx.y;
    int N = a.n[m];
    int e = blockIdx.x * 256 + threadIdx.x;
    if (e >= 128 * N) return;
    int sh = (N == 128) ? 7 : 6;
    int k = e >> sh;
    int n = e & (N - 1);
    float v = a.src[m][e];
    unsigned short h, l;
    splitf(v, h, l);
    a.dh[m][n * 128 + k] = h;
    a.dl[m][n * 128 + k] = l;
}

// ---------------- MFMA GEMM (LDS-staged, fused P+Q) ----------------
// BM=64 rows/block, 4 waves. A-tile (hi+lo bf16) staged in LDS once per block;
// fragments via ds_read_b128 (bounded regs; R9 post-mortem: register-resident B
// blew the VGPR budget -> compiler spilled -> serial reload stalls).
// Wave w: matrix = w>>1 (0->P via W1, 1->Q via W2), col half = w&1.
// LDS layout [col16][row] with column stride (64+1) -> conflict-free b128 reads.
// kt loop NOT unrolled: only 8 B-frags (32 VGPRs) live at a time, streamed from L2.
template <int BN, int NT, bool SPLITX>
__global__ __launch_bounds__(256) void gemm_lds(
    const float* __restrict__ X,
    const unsigned short* __restrict__ Ah, const unsigned short* __restrict__ Al,
    const unsigned short* __restrict__ W1h, const unsigned short* __restrict__ W1l,
    const unsigned short* __restrict__ W2h, const unsigned short* __restrict__ W2l,
    const float* __restrict__ bias, __half* __restrict__ P, float* __restrict__ Q, int M) {
    __shared__ short8 As[2][16 * 65];   // [hi/lo][col16*65 + row], 33.3 KB

    const int tid = threadIdx.x;
    const int wave = tid >> 6;
    const int lane = tid & 63;
    const int l15 = lane & 15;
    const int q = lane >> 4;
    const int m0 = blockIdx.x * 64;

    // ---- stage A tile into LDS (cooperative, coalesced) ----
    if constexpr (SPLITX) {
        // x fp32 [M][128]; each thread: 8 floats -> one hi slot + one lo slot
#pragma unroll
        for (int it = 0; it < 4; ++it) {
            int s = it * 256 + tid;          // 0..1023
            int row = s >> 4, col16 = s & 15;
            int gr = min(m0 + row, M - 1);
            const float4* xp = (const float4*)X + (size_t)gr * 32 + col16 * 2;
            float4 v0 = xp[0], v1 = xp[1];
            float fv[8] = {v0.x, v0.y, v0.z, v0.w, v1.x, v1.y, v1.z, v1.w};
            short8 h, l;
#pragma unroll
            for (int j = 0; j < 8; ++j) {
                unsigned short hh_, ll_;
                splitf(fv[j], hh_, ll_);
                h[j] = (short)hh_;
                l[j] = (short)ll_;
            }
            As[0][col16 * 65 + row] = h;
            As[1][col16 * 65 + row] = l;
        }
    } else {
#pragma unroll
        for (int it = 0; it < 8; ++it) {
            int s = it * 256 + tid;          // 0..2047
            int arr = s >> 10;
            int sp = s & 1023;
            int row = sp >> 4, col16 = sp & 15;
            int gr = min(m0 + row, M - 1);
            const unsigned short* src = (arr ? Al : Ah) + (size_t)gr * 128 + col16 * 8;
            As[arr][col16 * 65 + row] = *(const short8*)src;
        }
    }
    __syncthreads();

    // ---- wave assignment ----
    const int isQ = wave >> 1;
    const int colbase = (wave & 1) * (NT * 16);
    const unsigned short* Wh = isQ ? W2h : W1h;
    const unsigned short* Wl = isQ ? W2l : W1l;

    float bvs[NT];
#pragma unroll
    for (int nt = 0; nt < NT; ++nt) bvs[nt] = isQ ? bias[colbase + nt * 16 + l15] : 0.f;

    f32x4 acc[4][NT] = {};   // [mt][nt]

#pragma unroll 1
    for (int kt = 0; kt < 4; ++kt) {
        // B fragments for this kt only (streamed from L2)
        short8 Bh[NT], Bl[NT];
#pragma unroll
        for (int nt = 0; nt < NT; ++nt) {
            int c = colbase + nt * 16 + l15;
            int off = c * 128 + kt * 32 + q * 8;
            Bh[nt] = *(const short8*)(Wh + off);
            Bl[nt] = *(const short8*)(Wl + off);
        }
#pragma unroll
        for (int mt = 0; mt < 4; ++mt) {
            int ai = (kt * 4 + q) * 65 + mt * 16 + l15;
            short8 Afh = As[0][ai];
            short8 Afl = As[1][ai];
#pragma unroll
            for (int nt = 0; nt < NT; ++nt) {
                acc[mt][nt] = __builtin_amdgcn_mfma_f32_16x16x32_bf16(Afh, Bh[nt], acc[mt][nt], 0, 0, 0);
                acc[mt][nt] = __builtin_amdgcn_mfma_f32_16x16x32_bf16(Afh, Bl[nt], acc[mt][nt], 0, 0, 0);
                acc[mt][nt] = __builtin_amdgcn_mfma_f32_16x16x32_bf16(Afl, Bh[nt], acc[mt][nt], 0, 0, 0);
            }
        }
    }

    // ---- store ----
#pragma unroll
    for (int mt = 0; mt < 4; ++mt) {
        int orow = m0 + mt * 16 + q * 4;
#pragma unroll
        for (int nt = 0; nt < NT; ++nt) {
            int col = colbase + nt * 16 + l15;
#pragma unroll
            for (int r = 0; r < 4; ++r) {
                int rr = orow + r;
                if (rr < M) {
                    if (isQ) Q[(size_t)rr * BN + col] = acc[mt][nt][r] + bvs[nt];
                    else P[(size_t)rr * BN + col] = __float2half(acc[mt][nt][r]);
                }
            }
        }
    }
}

// ---------------- fused aggregation 128-dim, fp16 gather ----------------
__global__ __launch_bounds__(256) void agg_fused128(
    const __half* __restrict__ P, const float* __restrict__ Q,
    const int* __restrict__ row_ptr, const int* __restrict__ csr,
    const float* __restrict__ inv_deg, unsigned short* __restrict__ Hh,
    unsigned short* __restrict__ Hl, int n_nodes) {
    int node = (blockIdx.x * blockDim.x + threadIdx.x) >> 6;
    int lane = threadIdx.x & 63;
    if (node >= n_nodes) return;
    int beg = row_ptr[node], end = row_ptr[node + 1];
    const int half = lane >> 5;
    const int l = lane & 31;
    float a[4][4] = {};
    int e = beg;
    for (; e + 8 <= end; e += 8) {
#pragma unroll
        for (int j = 0; j < 4; ++j) {
            int s = csr[e + 2 * j + half];
            uint2 raw = *(const uint2*)(P + (size_t)s * 128 + l * 4);
            float2 f01 = __half22float2(*reinterpret_cast<__half2*>(&raw.x));
            float2 f23 = __half22float2(*reinterpret_cast<__half2*>(&raw.y));
            a[j][0] += f01.x; a[j][1] += f01.y; a[j][2] += f23.x; a[j][3] += f23.y;
        }
    }
    for (; e < end; e += 2) {
        int idx = e + half;
        if (idx < end) {
            int s = csr[idx];
            uint2 raw = *(const uint2*)(P + (size_t)s * 128 + l * 4);
            float2 f01 = __half22float2(*reinterpret_cast<__half2*>(&raw.x));
            float2 f23 = __half22float2(*reinterpret_cast<__half2*>(&raw.y));
            a[0][0] += f01.x; a[0][1] += f01.y; a[0][2] += f23.x; a[0][3] += f23.y;
        }
    }
    float s0 = (a[0][0] + a[1][0]) + (a[2][0] + a[3][0]);
    float s1 = (a[0][1] + a[1][1]) + (a[2][1] + a[3][1]);
    float s2 = (a[0][2] + a[1][2]) + (a[2][2] + a[3][2]);
    float s3 = (a[0][3] + a[1][3]) + (a[2][3] + a[3][3]);
    s0 += __shfl_xor(s0, 32);
    s1 += __shfl_xor(s1, 32);
    s2 += __shfl_xor(s2, 32);
    s3 += __shfl_xor(s3, 32);
    if (lane < 32) {
        float w = inv_deg[node];
        float4 qv = ((const float4*)Q)[(size_t)node * 32 + l];
        float h0 = fmaxf(fmaf(s0, w, qv.x), 0.f);
        float h1 = fmaxf(fmaf(s1, w, qv.y), 0.f);
        float h2 = fmaxf(fmaf(s2, w, qv.z), 0.f);
        float h3 = fmaxf(fmaf(s3, w, qv.w), 0.f);
        ushort4 hv, lv;
        splitf(h0, hv.x, lv.x);
        splitf(h1, hv.y, lv.y);
        splitf(h2, hv.z, lv.z);
        splitf(h3, hv.w, lv.w);
        ((ushort4*)Hh)[(size_t)node * 32 + l] = hv;
        ((ushort4*)Hl)[(size_t)node * 32 + l] = lv;
    }
}

// ---------------- fused aggregation 64-dim (fp16 gather) + output head ----------------
__global__ __launch_bounds__(256) void agg64_head(
    const __half* __restrict__ P, const float* __restrict__ Q,
    const int* __restrict__ row_ptr, const int* __restrict__ csr,
    const float* __restrict__ inv_deg, const float* __restrict__ Wo,
    const float* __restrict__ bo, float* __restrict__ out, int n_nodes) {
    int node = (blockIdx.x * blockDim.x + threadIdx.x) >> 6;
    int lane = threadIdx.x & 63;
    if (node >= n_nodes) return;
    int beg = row_ptr[node], end = row_ptr[node + 1];
    const int quarter = lane >> 4;
    const int l = lane & 15;
    float a[2][4] = {};
    int e = beg;
    for (; e + 8 <= end; e += 8) {
#pragma unroll
        for (int j = 0; j < 2; ++j) {
            int s = csr[e + 4 * j + quarter];
            uint2 raw = *(const uint2*)(P + (size_t)s * 64 + l * 4);
            float2 f01 = __half22float2(*reinterpret_cast<__half2*>(&raw.x));
            float2 f23 = __half22float2(*reinterpret_cast<__half2*>(&raw.y));
            a[j][0] += f01.x; a[j][1] += f01.y; a[j][2] += f23.x; a[j][3] += f23.y;
        }
    }
    for (; e < end; e += 4) {
        int idx = e + quarter;
        if (idx < end) {
            int s = csr[idx];
            uint2 raw = *(const uint2*)(P + (size_t)s * 64 + l * 4);
            float2 f01 = __half22float2(*reinterpret_cast<__half2*>(&raw.x));
            float2 f23 = __half22float2(*reinterpret_cast<__half2*>(&raw.y));
            a[0][0] += f01.x; a[0][1] += f01.y; a[0][2] += f23.x; a[0][3] += f23.y;
        }
    }
    float s0 = a[0][0] + a[1][0];
    float s1 = a[0][1] + a[1][1];
    float s2 = a[0][2] + a[1][2];
    float s3 = a[0][3] + a[1][3];
    s0 += __shfl_xor(s0, 16); s0 += __shfl_xor(s0, 32);
    s1 += __shfl_xor(s1, 16); s1 += __shfl_xor(s1, 32);
    s2 += __shfl_xor(s2, 16); s2 += __shfl_xor(s2, 32);
    s3 += __shfl_xor(s3, 16); s3 += __shfl_xor(s3, 32);
    if (lane < 16) {
        float w = inv_deg[node];
        float4 qv = ((const float4*)Q)[(size_t)node * 16 + l];
        float h0 = fmaxf(fmaf(s0, w, qv.x), 0.f);
        float h1 = fmaxf(fmaf(s1, w, qv.y), 0.f);
        float h2 = fmaxf(fmaf(s2, w, qv.z), 0.f);
        float h3 = fmaxf(fmaf(s3, w, qv.w), 0.f);
        const float4* Wo4 = (const float4*)Wo;
        float4 w0 = Wo4[4 * l + 0], w1 = Wo4[4 * l + 1], w2 = Wo4[4 * l + 2], w3 = Wo4[4 * l + 3];
        float c0 = h0 * w0.x + h1 * w1.x + h2 * w2.x + h3 * w3.x;
        float c1 = h0 * w0.y + h1 * w1.y + h2 * w2.y + h3 * w3.y;
        float c2 = h0 * w0.z + h1 * w1.z + h2 * w2.z + h3 * w3.z;
        float c3 = h0 * w0.w + h1 * w1.w + h2 * w2.w + h3 * w3.w;
#pragma unroll
        for (int m = 8; m > 0; m >>= 1) {
            c0 += __shfl_xor(c0, m);
            c1 += __shfl_xor(c1, m);
            c2 += __shfl_xor(c2, m);
            c3 += __shfl_xor(c3, m);
        }
        if (l == 0) {
            float4 r;
            r.x = c0 + bo[0];
            r.y = c1 + bo[1];
            r.z = c2 + bo[2];
            r.w = c3 + bo[3];
            ((float4*)out)[node] = r;
        }
    }
}

extern "C" void kernel_launch(void* const* d_in, const int* in_sizes, int n_in,
                              void* d_out, int out_size, void* d_ws, size_t ws_size,
                              hipStream_t stream) {
    const float* x = (const float*)d_in[0];
    const int* ei = (const int*)d_in[1];
    const float* wl0 = (const float*)d_in[3];
    const float* wr0 = (const float*)d_in[4];
    const float* b0 = (const float*)d_in[5];
    const float* wl1 = (const float*)d_in[6];
    const float* wr1 = (const float*)d_in[7];
    const float* b1 = (const float*)d_in[8];
    const float* wl2 = (const float*)d_in[9];
    const float* wr2 = (const float*)d_in[10];
    const float* b2 = (const float*)d_in[11];
    const float* wo = (const float*)d_in[12];
    const float* bo = (const float*)d_in[13];

    const int n_nodes = in_sizes[0] / D;   // 50000
    const int n_edges = in_sizes[1] / 2;   // 800000
    const int* srcp = ei;
    const int* dstp = ei + n_edges;

    char* ws = (char*)d_ws;
    size_t off = 0;
    auto carve = [&](size_t bytes) -> void* {
        void* p = ws + off;
        off = (off + bytes + 255) & ~(size_t)255;
        return p;
    };
    int* deg = (int*)carve((size_t)n_nodes * 4);
    int* row_ptr = (int*)carve((size_t)(n_nodes + 1) * 4);
    int* partials = (int*)carve(256 * 4);
    float* inv_deg = (float*)carve((size_t)n_nodes * 4);
    int* csr = (int*)carve((size_t)n_edges * 4);
    __half* Pbuf = (__half*)carve((size_t)n_nodes * D * 2);   // 12.8 MB
    float* Qbuf = (float*)carve((size_t)n_nodes * D * 4);     // 25.6 MB
    unsigned short* hh = (unsigned short*)carve((size_t)n_nodes * D * 2);
    unsigned short* hl = (unsigned short*)carve((size_t)n_nodes * D * 2);
    unsigned short* wt = (unsigned short*)carve((size_t)(4 * 128 * 128 + 2 * 64 * 128) * 2 * 2);
    unsigned short* wl0h = wt;
    unsigned short* wl0l = wl0h + 128 * 128;
    unsigned short* wr0h = wl0l + 128 * 128;
    unsigned short* wr0l = wr0h + 128 * 128;
    unsigned short* wl1h = wr0l + 128 * 128;
    unsigned short* wl1l = wl1h + 128 * 128;
    unsigned short* wr1h = wl1l + 128 * 128;
    unsigned short* wr1l = wr1h + 128 * 128;
    unsigned short* wl2h = wr1l + 128 * 128;
    unsigned short* wl2l = wl2h + 64 * 128;
    unsigned short* wr2h = wl2l + 64 * 128;
    unsigned short* wr2l = wr2h + 64 * 128;

    // CSR-build scratch aliases P/Q (dead until first GEMM):
    const int rr = (n_nodes + NRANGE - 1) / NRANGE;        // 6250
    const int ch = (n_edges + NCHUNK - 1) / NCHUNK;        // 12500
    int* hist = (int*)Qbuf;
    int* basep = (int*)Pbuf;

    const int nchunk_scan = (n_nodes + SCAN_CHUNK - 1) / SCAN_CHUNK;

    hist_count<<<NRANGE * NCHUNK, 1024, 0, stream>>>(dstp, hist, n_edges, n_nodes, rr, ch);
    deg_sum<<<(n_nodes + 255) / 256, 256, 0, stream>>>(hist, deg, n_nodes, rr);
    partial_sums<<<nchunk_scan, 256, 0, stream>>>(deg, partials, n_nodes);
    scan_partials<<<1, 64, 0, stream>>>(partials, nchunk_scan, row_ptr + n_nodes);
    scan_chunks<<<nchunk_scan, 256, 0, stream>>>(deg, partials, row_ptr, inv_deg, n_nodes);
    base_fill<<<(n_nodes + 255) / 256, 256, 0, stream>>>(hist, row_ptr, basep, n_nodes, rr);
    fill_part<<<NRANGE * NCHUNK, 1024, 0, stream>>>(srcp, dstp, basep, csr, n_edges, n_nodes, rr, ch);

    WSplitArgs wa;
    wa.src[0] = wl0; wa.dh[0] = wl0h; wa.dl[0] = wl0l; wa.n[0] = 128;
    wa.src[1] = wr0; wa.dh[1] = wr0h; wa.dl[1] = wr0l; wa.n[1] = 128;
    wa.src[2] = wl1; wa.dh[2] = wl1h; wa.dl[2] = wl1l; wa.n[2] = 128;
    wa.src[3] = wr1; wa.dh[3] = wr1h; wa.dl[3] = wr1l; wa.n[3] = 128;
    wa.src[4] = wl2; wa.dh[4] = wl2h; wa.dl[4] = wl2l; wa.n[4] = 64;
    wa.src[5] = wr2; wa.dh[5] = wr2h; wa.dl[5] = wr2l; wa.n[5] = 64;
    split_w<<<dim3(64, 6), 256, 0, stream>>>(wa);

    const int agg_blocks = (n_nodes * 64 + 255) / 256;
    const int gemm_blocks = (n_nodes + 63) / 64;   // 782

    // layer 0: A = x (fp32, split during LDS staging)
    gemm_lds<128, 4, true><<<gemm_blocks, 256, 0, stream>>>(
        x, nullptr, nullptr, wl0h, wl0l, wr0h, wr0l, b0, Pbuf, Qbuf, n_nodes);
    agg_fused128<<<agg_blocks, 256, 0, stream>>>(Pbuf, Qbuf, row_ptr, csr, inv_deg, hh, hl, n_nodes);
    // layer 1
    gemm_lds<128, 4, false><<<gemm_blocks, 256, 0, stream>>>(
        nullptr, hh, hl, wl1h, wl1l, wr1h, wr1l, b1, Pbuf, Qbuf, n_nodes);
    agg_fused128<<<agg_blocks, 256, 0, stream>>>(Pbuf, Qbuf, row_ptr, csr, inv_deg, hh, hl, n_nodes);
    // layer 2 (each matrix 64 cols)
    gemm_lds<64, 2, false><<<gemm_blocks, 256, 0, stream>>>(
        nullptr, hh, hl, wl2h, wl2l, wr2h, wr2l, b2, Pbuf, Qbuf, n_nodes);
    agg64_head<<<agg_blocks, 256, 0, stream>>>(Pbuf, Qbuf, row_ptr, csr, inv_deg,
                                               wo, bo, (float*)d_out, n_nodes);
}